// Round 2
// baseline (444.757 us; speedup 1.0000x reference)
//
#include <hip/hip_runtime.h>

// Problem sizes (fixed by reference): B=8, N=20, T=300, U=64, H=512, NT=6000
#define BB 8
#define NN 20
#define TT 300
#define UU 64
#define HH 512
#define NT 6000

// ws layout (float slots):
//  scores : [B][NT][U]     off 0          (3,072,000)  raw scores (f32)
//  tmax   : [B][U][N]      off 3,072,000  (10,240)
//  tsum   : [B][U][N]      off 3,082,240  (10,240)
//  W      : [B][U][1024]   off 3,092,480  (524,288)   [0:512]=q f32, [512:1024]=aggdoc f32
//  flag   : int            off 3,616,768  (4)
//  QsH/QsL: bf16 [B][U][512] x2  off 3,616,772 / 3,747,844  (131,072 fl each)
//  Pt     : bf16 [B][NT][U]      off 3,878,916 (1,536,000 fl)
//  PaH/PaL: bf16 [B][NT][U] x2   off 5,414,916 / 6,950,916
//  WtH/WtL: bf16 [B][1024][64]x2 off 8,486,916 / 8,749,060  (262,144 fl each)
//  total = 9,011,204 floats = 36.0 MB (ws observed ~786 MB)

typedef __attribute__((ext_vector_type(4))) float f32x4;
typedef __attribute__((ext_vector_type(8))) short s16x8;

__device__ __forceinline__ float bf2f(unsigned short u) {
  union { unsigned int i; float f; } c; c.i = ((unsigned int)u) << 16; return c.f;
}
__device__ __forceinline__ unsigned short f2bf(float f) {
  union { float f; unsigned int i; } c; c.f = f;
  unsigned int u = c.i;
  unsigned int r = (u + 0x7fffu + ((u >> 16) & 1u)) >> 16;  // RNE
  return (unsigned short)r;
}
// split-bf16: x ~= hi + lo, each exactly representable in bf16. Using
// hi*hi' + hi*lo' + lo*hi' in MFMA keeps relative error ~2^-18 (f32-like).
__device__ __forceinline__ void splitbf(float x, unsigned short& hi, unsigned short& lo) {
  hi = f2bf(x);
  lo = f2bf(x - bf2f(hi));
}
__device__ __forceinline__ f32x4 mfma16(s16x8 a, s16x8 b, f32x4 c) {
  return __builtin_amdgcn_mfma_f32_16x16x32_bf16(a, b, c, 0, 0, 0);
}

// ---------------- detect: are inputs f32 (1) or bf16 (0)? ----------------
__global__ __launch_bounds__(256) void kdetect(const unsigned short* __restrict__ d16,
                                               int* __restrict__ flag) {
  __shared__ int cnt[4];
  int t = threadIdx.x;
  unsigned short v = d16[t];
  int e = (v >> 7) & 0xFF;
  int weird = (e > 140 || (e < 110 && (v & 0x7FFFu) != 0)) ? 1 : 0;
  unsigned long long m = __ballot(weird);
  if ((t & 63) == 0) cnt[t >> 6] = __popcll(m);
  __syncthreads();
  if (t == 0) flag[0] = (cnt[0] + cnt[1] + cnt[2] + cnt[3] >= 32) ? 1 : 0;
}

// ---------------- K0: init W (q as f32, zero aggdoc half) + q split planes ----------
__global__ __launch_bounds__(256) void k0_init(const void* __restrict__ qv,
                                               const int* __restrict__ flag,
                                               float* __restrict__ W,
                                               unsigned short* __restrict__ QsH,
                                               unsigned short* __restrict__ QsL) {
  const int isf32 = *flag;
  int idx = blockIdx.x * 256 + threadIdx.x;  // B*U*1024 = 524288
  int h2 = idx & 1023;
  int bu = idx >> 10;
  float v = 0.0f;
  if (h2 < HH) {
    v = isf32 ? ((const float*)qv)[bu * HH + h2]
              : bf2f(((const unsigned short*)qv)[bu * HH + h2]);
    unsigned short hi, lo;
    splitbf(v, hi, lo);
    QsH[bu * HH + h2] = hi;
    QsL[bu * HH + h2] = lo;
  }
  W[idx] = v;
}

// ---------------- K1 (MFMA, split-bf16): scores = doc . q^T ----------------
// Tile: 128 doc rows x 64 u, 512 threads (8 waves), K=512 in 8 chunks of 64.
// A = q (m=u) loaded as fragments DIRECTLY from pre-split global planes (L2-hot).
// B = doc (n=doc-row) staged hi/lo in swizzled LDS (split done once at the f32 read).
__global__ __launch_bounds__(512) void k1_mfma(const void* __restrict__ docv,
                                               const unsigned short* __restrict__ QsH,
                                               const unsigned short* __restrict__ QsL,
                                               const int* __restrict__ flag,
                                               float* __restrict__ scores) {
  __shared__ __align__(16) unsigned short sDh[128 * 64], sDl[128 * 64];
  const int isf32 = *flag;
  const int b = blockIdx.y, kt = blockIdx.x;  // kt 0..46
  const int tid = threadIdx.x;
  const int lane = tid & 63, w = tid >> 6;
  const int l15 = lane & 15, l4 = lane >> 4;
  const int kmax = NT - kt * 128;  // 128, or 112 for last block
  const size_t dbase = (size_t)(b * NT + kt * 128) * HH;
  const size_t qrow0 = (size_t)b * UU * HH;
  const f32x4 zero = {0.f, 0.f, 0.f, 0.f};
  f32x4 acc[4] = {zero, zero, zero, zero};  // 4 u-tiles for this wave's 16 doc rows

  for (int hc = 0; hc < 8; ++hc) {
    if (hc) __syncthreads();
    // stage doc 128x64 hi/lo (split at read, swizzled LDS)
#pragma unroll
    for (int i = 0; i < 2; ++i) {
      int g = tid + 512 * i;  // 1024 groups of 8 elems (128 rows x 8 groups)
      int row = g >> 3, h8 = (g & 7) * 8;
      int addr = (row * 128 + h8 * 2) ^ ((row & 7) << 4);
      float v[8] = {0.f, 0.f, 0.f, 0.f, 0.f, 0.f, 0.f, 0.f};
      if (row < kmax) {
        size_t off = dbase + (size_t)row * HH + hc * 64 + h8;
        if (isf32) {
          const float* df = (const float*)docv;
          float4 a0 = *(const float4*)(df + off);
          float4 a1 = *(const float4*)(df + off + 4);
          v[0] = a0.x; v[1] = a0.y; v[2] = a0.z; v[3] = a0.w;
          v[4] = a1.x; v[5] = a1.y; v[6] = a1.z; v[7] = a1.w;
        } else {
          const unsigned short* db = (const unsigned short*)docv;
          ushort4 a0 = *(const ushort4*)(db + off);
          ushort4 a1 = *(const ushort4*)(db + off + 4);
          v[0] = bf2f(a0.x); v[1] = bf2f(a0.y); v[2] = bf2f(a0.z); v[3] = bf2f(a0.w);
          v[4] = bf2f(a1.x); v[5] = bf2f(a1.y); v[6] = bf2f(a1.z); v[7] = bf2f(a1.w);
        }
      }
      s16x8 vh, vl;
#pragma unroll
      for (int j = 0; j < 8; ++j) {
        unsigned short hh, ll; splitbf(v[j], hh, ll);
        vh[j] = (short)hh; vl[j] = (short)ll;
      }
      *(s16x8*)((char*)sDh + addr) = vh;
      *(s16x8*)((char*)sDl + addr) = vl;
    }
    __syncthreads();
    // q fragments straight from global split planes
    s16x8 qh[2][4], ql[2][4];
#pragma unroll
    for (int kb = 0; kb < 2; ++kb)
#pragma unroll
      for (int mt = 0; mt < 4; ++mt) {
        size_t qa = qrow0 + (size_t)(mt * 16 + l15) * HH + hc * 64 + kb * 32 + l4 * 8;
        qh[kb][mt] = *(const s16x8*)&QsH[qa];
        ql[kb][mt] = *(const s16x8*)&QsL[qa];
      }
#pragma unroll
    for (int kb = 0; kb < 2; ++kb) {
      const int off = kb * 64 + l4 * 16;
      const int brow = w * 16 + l15;  // this wave's doc rows
      const int ba = (brow * 128 + off) ^ ((brow & 7) << 4);
      s16x8 bh = *(const s16x8*)((const char*)sDh + ba);
      s16x8 bl = *(const s16x8*)((const char*)sDl + ba);
#pragma unroll
      for (int mt = 0; mt < 4; ++mt) {
        acc[mt] = mfma16(qh[kb][mt], bh, acc[mt]);
        acc[mt] = mfma16(qh[kb][mt], bl, acc[mt]);
        acc[mt] = mfma16(ql[kb][mt], bh, acc[mt]);
      }
    }
  }
  const int krow = w * 16 + l15;
  if (krow < kmax) {
    size_t ro = ((size_t)b * NT + kt * 128 + krow) * 64;
#pragma unroll
    for (int mt = 0; mt < 4; ++mt)
      *(f32x4*)&scores[ro + mt * 16 + l4 * 4] = acc[mt];
  }
}

// ---------------- K2b: per-(b,u,n) online max/sum over T with doc_mask ----------------
__global__ __launch_bounds__(256) void k2b_tstats(const float* __restrict__ scores,
                                                  const int* __restrict__ dm,
                                                  float* __restrict__ tmax,
                                                  float* __restrict__ tsum) {
  const int b = blockIdx.x / NN;
  const int n = blockIdx.x % NN;
  const int u = threadIdx.x & 63;
  const int tg = threadIdx.x >> 6;  // 0..3
  float m = -__builtin_inff(), s = 0.0f;
  for (int t = tg; t < TT; t += 4) {
    int dmv = dm[(b * NN + n) * TT + t];  // wave-uniform
    if (dmv) {
      float v = scores[((size_t)(b * NT) + n * TT + t) * 64 + u];
      if (v > m) { s = s * __expf(m - v) + 1.0f; m = v; }
      else s += __expf(v - m);
    }
  }
  __shared__ float sm[4][64], ss[4][64];
  sm[tg][u] = m; ss[tg][u] = s;
  __syncthreads();
  if (threadIdx.x < 64) {
    float M = sm[0][u];
#pragma unroll
    for (int i = 1; i < 4; ++i) M = fmaxf(M, sm[i][u]);
    float S = 0.0f;
#pragma unroll
    for (int i = 0; i < 4; ++i) {
      if (ss[i][u] > 0.0f) S += ss[i][u] * __expf(sm[i][u] - M);
    }
    tmax[(b * 64 + u) * NN + n] = M;
    tsum[(b * 64 + u) * NN + n] = S;
  }
}

// ---------------- K2c2: U-softmax -> Pa hi/lo (bf16 split) + t-weights -> Pt (bf16) ----
__global__ __launch_bounds__(256) void k2c2(const float* __restrict__ scores,
                                            const int* __restrict__ qm,
                                            const int* __restrict__ dm,
                                            const float* __restrict__ tmax,
                                            const float* __restrict__ tsum,
                                            unsigned short* __restrict__ PaH,
                                            unsigned short* __restrict__ PaL,
                                            unsigned short* __restrict__ Pt) {
  const int row = blockIdx.x * 4 + (threadIdx.x >> 6);  // 0..47999
  const int u = threadIdx.x & 63;
  const int b = row / NT;
  const int k = row - b * NT;
  const int n = k / TT;
  const float s = scores[(size_t)row * 64 + u];
  const int m = qm[b * 64 + u];
  float v = m ? s : -__builtin_inff();
#pragma unroll
  for (int o = 32; o > 0; o >>= 1) v = fmaxf(v, __shfl_xor(v, o, 64));
  float e = m ? __expf(s - v) : 0.0f;
  float sum = e;
#pragma unroll
  for (int o = 32; o > 0; o >>= 1) sum += __shfl_xor(sum, o, 64);
  float attn = (sum > 0.0f) ? (e / sum) : 0.0f;
  unsigned short hi, lo;
  splitbf(attn, hi, lo);
  PaH[(size_t)row * 64 + u] = hi;
  PaL[(size_t)row * 64 + u] = lo;
  float wgt = 0.0f;
  if (dm[b * NT + k]) {
    float S = tsum[(b * 64 + u) * NN + n];
    if (S > 0.0f) wgt = __expf(s - tmax[(b * 64 + u) * NN + n]) / S;
  }
  Pt[(size_t)row * 64 + u] = f2bf(wgt);
}

// ---------------- K3 (MFMA): aggdoc += Pt^T . doc (split-k atomics into W) ----------
// A = Pt^T (m=u), B = doc (n=h); doc hi/lo split. Staging: each thread loads a
// 4k x 4(u|h) register block, splits + transposes in registers, writes ushort4
// (8 B) columns into swizzled LDS -> 4x fewer LDS ops than scalar scatter.
__global__ __launch_bounds__(256) void k3_mfma(const unsigned short* __restrict__ Pt,
                                               const void* __restrict__ docv,
                                               const int* __restrict__ flag,
                                               float* __restrict__ W) {
  __shared__ __align__(16) unsigned short sDh[128 * 64], sDl[128 * 64];  // [h][k] bf16
  __shared__ __align__(16) unsigned short sP[64 * 64];                   // [u][k] bf16
  const int isf32 = *flag;
  const int b = blockIdx.z, hc = blockIdx.y, kc = blockIdx.x;  // (24,4,8)
  const int tid = threadIdx.x, lane = tid & 63, w = tid >> 6;
  const int l15 = lane & 15, l4 = lane >> 4;
  const int k0base = kc * 250, kend = k0base + 250;
  const f32x4 zero = {0.f, 0.f, 0.f, 0.f};
  f32x4 acc[4][2];
#pragma unroll
  for (int mt = 0; mt < 4; ++mt) { acc[mt][0] = zero; acc[mt][1] = zero; }

  for (int kb = k0base; kb < kend; kb += 64) {
    const int kn = min(64, kend - kb);
    if (kb != k0base) __syncthreads();
    // ---- Pt chunk: 4x4 register transpose -> sP[u][k]
    {
      const int ug = tid & 15, kg = tid >> 4;  // u-group, k-group
      ushort4 r[4];
#pragma unroll
      for (int rr = 0; rr < 4; ++rr) {
        int kk = kg * 4 + rr;
        ushort4 t = make_ushort4(0, 0, 0, 0);
        if (kk < kn) t = *(const ushort4*)&Pt[((size_t)b * NT + kb + kk) * 64 + ug * 4];
        r[rr] = t;
      }
      const unsigned short* rp = (const unsigned short*)r;  // r[rr] elem uu = rp[rr*4+uu]
#pragma unroll
      for (int uu = 0; uu < 4; ++uu) {
        int u = ug * 4 + uu;
        int addr = (u * 128 + kg * 8) ^ ((u & 7) << 4);
        ushort4 col = make_ushort4(rp[0 * 4 + uu], rp[1 * 4 + uu], rp[2 * 4 + uu], rp[3 * 4 + uu]);
        *(ushort4*)((char*)sP + addr) = col;
      }
    }
    // ---- doc chunk: 4x4 register split+transpose -> sDh/sDl[h][k]
#pragma unroll
    for (int i = 0; i < 2; ++i) {
      int s = tid + 256 * i;          // 512 tasks
      int hg = s & 31, kg = s >> 5;   // h-group (0..31), k-group (0..15)
      float rv[4][4];
#pragma unroll
      for (int rr = 0; rr < 4; ++rr) {
        int kk = kg * 4 + rr;
        float4 v = make_float4(0.f, 0.f, 0.f, 0.f);
        if (kk < kn) {
          size_t off = ((size_t)b * NT + kb + kk) * HH + hc * 128 + hg * 4;
          if (isf32) v = *(const float4*)((const float*)docv + off);
          else {
            ushort4 t = *(const ushort4*)((const unsigned short*)docv + off);
            v = make_float4(bf2f(t.x), bf2f(t.y), bf2f(t.z), bf2f(t.w));
          }
        }
        rv[rr][0] = v.x; rv[rr][1] = v.y; rv[rr][2] = v.z; rv[rr][3] = v.w;
      }
#pragma unroll
      for (int hh = 0; hh < 4; ++hh) {
        int hrow = hg * 4 + hh;
        int addr = (hrow * 128 + kg * 8) ^ ((hrow & 7) << 4);
        unsigned short h0, l0, h1, l1, h2, l2, h3, l3;
        splitbf(rv[0][hh], h0, l0);
        splitbf(rv[1][hh], h1, l1);
        splitbf(rv[2][hh], h2, l2);
        splitbf(rv[3][hh], h3, l3);
        *(ushort4*)((char*)sDh + addr) = make_ushort4(h0, h1, h2, h3);
        *(ushort4*)((char*)sDl + addr) = make_ushort4(l0, l1, l2, l3);
      }
    }
    __syncthreads();
#pragma unroll
    for (int ks = 0; ks < 2; ++ks) {
      const int off = ks * 64 + l4 * 16;
      s16x8 bh[2], bl[2];
#pragma unroll
      for (int nt = 0; nt < 2; ++nt) {
        int r = w * 32 + nt * 16 + l15;
        int a = (r * 128 + off) ^ ((r & 7) << 4);
        bh[nt] = *(const s16x8*)((const char*)sDh + a);
        bl[nt] = *(const s16x8*)((const char*)sDl + a);
      }
#pragma unroll
      for (int mt = 0; mt < 4; ++mt) {
        int r = mt * 16 + l15;
        int a = (r * 128 + off) ^ ((r & 7) << 4);
        s16x8 pa = *(const s16x8*)((const char*)sP + a);
#pragma unroll
        for (int nt = 0; nt < 2; ++nt) {
          acc[mt][nt] = mfma16(pa, bh[nt], acc[mt][nt]);
          acc[mt][nt] = mfma16(pa, bl[nt], acc[mt][nt]);
        }
      }
    }
  }
#pragma unroll
  for (int mt = 0; mt < 4; ++mt)
#pragma unroll
    for (int nt = 0; nt < 2; ++nt)
#pragma unroll
      for (int j = 0; j < 4; ++j) {
        int u = mt * 16 + l4 * 4 + j;
        int h = hc * 128 + w * 32 + nt * 16 + l15;
        atomicAdd(&W[((size_t)b * 64 + u) * 1024 + 512 + h], acc[mt][nt][j]);
      }
}

// ---------------- K3.5: W f32 [b][u][1024] -> Wt hi/lo bf16 [b][1024][64] -----------
__global__ __launch_bounds__(256) void k35_wt(const float* __restrict__ W,
                                              unsigned short* __restrict__ WtH,
                                              unsigned short* __restrict__ WtL) {
  __shared__ float sW[64][68];
  const int b = blockIdx.y, hck = blockIdx.x;  // 16 chunks of 64 h2
  const int tid = threadIdx.x;
#pragma unroll
  for (int i = 0; i < 4; ++i) {
    int g = tid + 256 * i;
    int u = g >> 4, c4 = (g & 15) * 4;
    *(float4*)&sW[u][c4] = *(const float4*)&W[((size_t)b * 64 + u) * 1024 + hck * 64 + c4];
  }
  __syncthreads();
  const int h = tid >> 2, ug = tid & 3;
  s16x8 oh[2], ol[2];
#pragma unroll
  for (int p = 0; p < 2; ++p)
#pragma unroll
    for (int j = 0; j < 8; ++j) {
      unsigned short hh, ll;
      splitbf(sW[ug * 16 + p * 8 + j][h], hh, ll);
      oh[p][j] = (short)hh; ol[p][j] = (short)ll;
    }
  size_t ob = ((size_t)b * 1024 + hck * 64 + h) * 64 + ug * 16;
  *(s16x8*)&WtH[ob] = oh[0];
  *(s16x8*)&WtH[ob + 8] = oh[1];
  *(s16x8*)&WtL[ob] = ol[0];
  *(s16x8*)&WtL[ob + 8] = ol[1];
}

// ---------------- K4 (MFMA): out = Pa . W, fragments straight from L2 ----------------
// A = Wt (m=h2), B = Pa (n=doc-row); contraction k=u=64 -> both 16B-contiguous,
// no LDS, no barriers. hi/lo split on both sides (3 MFMAs).
__global__ __launch_bounds__(256) void k4_mfma(const unsigned short* __restrict__ PaH,
                                               const unsigned short* __restrict__ PaL,
                                               const unsigned short* __restrict__ WtH,
                                               const unsigned short* __restrict__ WtL,
                                               const int* __restrict__ flag,
                                               void* __restrict__ outv) {
  const int isf32 = *flag;
  const int b = blockIdx.z, ht = blockIdx.y, kt = blockIdx.x;  // (24,16,8)
  const int tid = threadIdx.x, lane = tid & 63, w = tid >> 6;
  const int l15 = lane & 15, l4 = lane >> 4;
  const int h0 = ht * 64;
  const int kr0 = kt * 256 + w * 64;
  const f32x4 zero = {0.f, 0.f, 0.f, 0.f};
  f32x4 acc[4][4];
#pragma unroll
  for (int mt = 0; mt < 4; ++mt)
#pragma unroll
    for (int nt = 0; nt < 4; ++nt) acc[mt][nt] = zero;
#pragma unroll
  for (int kb = 0; kb < 2; ++kb) {
    s16x8 ah[4], al[4];
#pragma unroll
    for (int mt = 0; mt < 4; ++mt) {
      size_t a = ((size_t)b * 1024 + h0 + mt * 16 + l15) * 64 + kb * 32 + l4 * 8;
      ah[mt] = *(const s16x8*)&WtH[a];
      al[mt] = *(const s16x8*)&WtL[a];
    }
#pragma unroll
    for (int nt = 0; nt < 4; ++nt) {
      int krow = kr0 + nt * 16 + l15;
      int krc = krow < NT ? krow : NT - 1;  // clamp tail reads (cols never stored)
      size_t pb = ((size_t)b * NT + krc) * 64 + kb * 32 + l4 * 8;
      s16x8 bh = *(const s16x8*)&PaH[pb];
      s16x8 bl = *(const s16x8*)&PaL[pb];
#pragma unroll
      for (int mt = 0; mt < 4; ++mt) {
        acc[mt][nt] = mfma16(ah[mt], bh, acc[mt][nt]);
        acc[mt][nt] = mfma16(ah[mt], bl, acc[mt][nt]);
        acc[mt][nt] = mfma16(al[mt], bh, acc[mt][nt]);
      }
    }
  }
#pragma unroll
  for (int nt = 0; nt < 4; ++nt) {
    int krow = kr0 + nt * 16 + l15;
    if (krow < NT) {
      size_t ob = ((size_t)b * NT + krow) * 1024 + h0;
#pragma unroll
      for (int mt = 0; mt < 4; ++mt) {
        int h2 = mt * 16 + l4 * 4;
        if (isf32) {
          *(f32x4*)((float*)outv + ob + h2) = acc[mt][nt];
        } else {
          ushort4 o;
          o.x = f2bf(acc[mt][nt][0]); o.y = f2bf(acc[mt][nt][1]);
          o.z = f2bf(acc[mt][nt][2]); o.w = f2bf(acc[mt][nt][3]);
          *(ushort4*)((unsigned short*)outv + ob + h2) = o;
        }
      }
    }
  }
}

// ---------------- fallback K2 (in-place U-softmax only, f32) ----------------
__global__ __launch_bounds__(256) void k2_softmax_u(float* __restrict__ scores,
                                                    const int* __restrict__ qm) {
  const int row = blockIdx.x * 4 + (threadIdx.x >> 6);
  const int u = threadIdx.x & 63;
  const int b = row / NT;
  const float s = scores[(size_t)row * 64 + u];
  const int m = qm[b * 64 + u];
  float v = m ? s : -__builtin_inff();
#pragma unroll
  for (int o = 32; o > 0; o >>= 1) v = fmaxf(v, __shfl_xor(v, o, 64));
  float e = m ? __expf(s - v) : 0.0f;
  float sum = e;
#pragma unroll
  for (int o = 32; o > 0; o >>= 1) sum += __shfl_xor(sum, o, 64);
  scores[(size_t)row * 64 + u] = (sum > 0.0f) ? (e / sum) : 0.0f;
}

// ---------------- fallback K3 (original fused aggdoc, f32) ----------------
__global__ __launch_bounds__(256) void k3_aggdoc(const float* __restrict__ scores,
                                                 const void* __restrict__ docv,
                                                 const int* __restrict__ dm,
                                                 const float* __restrict__ tmax,
                                                 const float* __restrict__ tsum,
                                                 const int* __restrict__ flag,
                                                 float* __restrict__ W) {
  __shared__ float wL[32][68];
  __shared__ float dL[32][68];
  const int isf32 = *flag;
  const int b = blockIdx.z, hc = blockIdx.y, kc = blockIdx.x;  // (16,8,8)
  const int tid = threadIdx.x;
  const int th = tid & 15, tuq = tid >> 4;
  float acc[4][4] = {};
  const int k0base = kc * 375, kend = k0base + 375;
  for (int k0 = k0base; k0 < kend; k0 += 32) {
    const int kn = min(32, kend - k0);
#pragma unroll
    for (int i = 0; i < 8; ++i) {
      int idx = tid + 256 * i;
      int kk = idx >> 6, uu = idx & 63;
      float wv = 0.0f;
      if (kk < kn) {
        int k = k0 + kk;
        int n = k / TT;
        if (dm[b * NT + k]) {
          float S = tsum[(b * 64 + uu) * NN + n];
          if (S > 0.0f) {
            float M = tmax[(b * 64 + uu) * NN + n];
            wv = __expf(scores[((size_t)(b * NT) + k) * 64 + uu] - M) / S;
          }
        }
      }
      wL[kk][uu] = wv;
    }
#pragma unroll
    for (int i = 0; i < 2; ++i) {
      int g = tid + 256 * i;
      int kk = g >> 4, c4 = (g & 15) * 4;
      float4 v = make_float4(0.f, 0.f, 0.f, 0.f);
      if (kk < kn) {
        size_t off = ((size_t)(b * NT) + k0 + kk) * HH + hc * 64 + c4;
        if (isf32) v = *(const float4*)((const float*)docv + off);
        else {
          ushort4 t4 = *(const ushort4*)((const unsigned short*)docv + off);
          v = make_float4(bf2f(t4.x), bf2f(t4.y), bf2f(t4.z), bf2f(t4.w));
        }
      }
      *(float4*)&dL[kk][c4] = v;
    }
    __syncthreads();
    for (int kk = 0; kk < kn; ++kk) {
      float4 w4 = *(const float4*)&wL[kk][tuq * 4];
      float4 d4 = *(const float4*)&dL[kk][th * 4];
      acc[0][0] += w4.x * d4.x; acc[0][1] += w4.x * d4.y; acc[0][2] += w4.x * d4.z; acc[0][3] += w4.x * d4.w;
      acc[1][0] += w4.y * d4.x; acc[1][1] += w4.y * d4.y; acc[1][2] += w4.y * d4.z; acc[1][3] += w4.y * d4.w;
      acc[2][0] += w4.z * d4.x; acc[2][1] += w4.z * d4.y; acc[2][2] += w4.z * d4.z; acc[2][3] += w4.z * d4.w;
      acc[3][0] += w4.w * d4.x; acc[3][1] += w4.w * d4.y; acc[3][2] += w4.w * d4.z; acc[3][3] += w4.w * d4.w;
    }
    __syncthreads();
  }
#pragma unroll
  for (int i = 0; i < 4; ++i) {
#pragma unroll
    for (int j = 0; j < 4; ++j) {
      size_t addr = ((size_t)(b * 64) + tuq * 4 + i) * 1024 + 512 + hc * 64 + th * 4 + j;
      atomicAdd(&W[addr], acc[i][j]);
    }
  }
}

// ---------------- fallback K4 (f32 VALU out-GEMM) ----------------
__global__ __launch_bounds__(256) void k4_out(const float* __restrict__ attn,
                                              const float* __restrict__ W,
                                              const int* __restrict__ flag,
                                              void* __restrict__ outv) {
  __shared__ float sAt[64][68];
  __shared__ float sWt[64][132];
  const int isf32 = *flag;
  const int b = blockIdx.z;
  const int kt = blockIdx.x;
  const int ht = blockIdx.y;
  const int tid = threadIdx.x;
  const int th2 = tid & 15, tkq = tid >> 4;
#pragma unroll
  for (int i = 0; i < 4; ++i) {
    int g = tid + 256 * i;
    int row = g >> 4, c4 = (g & 15) * 4;
    int k = kt * 64 + row;
    float4 v = make_float4(0.f, 0.f, 0.f, 0.f);
    if (k < NT) v = *(const float4*)&attn[((size_t)(b * NT) + k) * 64 + c4];
    *(float4*)&sAt[row][c4] = v;
  }
#pragma unroll
  for (int i = 0; i < 8; ++i) {
    int g = tid + 256 * i;
    int row = g >> 5, c4 = (g & 31) * 4;
    float4 wv = *(const float4*)&W[((size_t)(b * 64) + row) * 1024 + ht * 128 + c4];
    *(float4*)&sWt[row][c4] = wv;
  }
  __syncthreads();
  float acc[4][8] = {};
#pragma unroll 4
  for (int u = 0; u < 64; u += 4) {
    float a[4][4];
#pragma unroll
    for (int i = 0; i < 4; ++i)
      *(float4*)a[i] = *(const float4*)&sAt[tkq * 4 + i][u];
#pragma unroll
    for (int r = 0; r < 4; ++r) {
      float4 w0 = *(const float4*)&sWt[u + r][th2 * 4];
      float4 w1 = *(const float4*)&sWt[u + r][64 + th2 * 4];
#pragma unroll
      for (int i = 0; i < 4; ++i) {
        acc[i][0] += a[i][r] * w0.x; acc[i][1] += a[i][r] * w0.y;
        acc[i][2] += a[i][r] * w0.z; acc[i][3] += a[i][r] * w0.w;
        acc[i][4] += a[i][r] * w1.x; acc[i][5] += a[i][r] * w1.y;
        acc[i][6] += a[i][r] * w1.z; acc[i][7] += a[i][r] * w1.w;
      }
    }
  }
#pragma unroll
  for (int i = 0; i < 4; ++i) {
    int k = kt * 64 + tkq * 4 + i;
    if (k < NT) {
      size_t off = ((size_t)(b * NT) + k) * 1024 + ht * 128 + th2 * 4;
      if (isf32) {
        *(float4*)((float*)outv + off) = make_float4(acc[i][0], acc[i][1], acc[i][2], acc[i][3]);
        *(float4*)((float*)outv + off + 64) = make_float4(acc[i][4], acc[i][5], acc[i][6], acc[i][7]);
      } else {
        ushort4 o0, o1;
        o0.x = f2bf(acc[i][0]); o0.y = f2bf(acc[i][1]); o0.z = f2bf(acc[i][2]); o0.w = f2bf(acc[i][3]);
        o1.x = f2bf(acc[i][4]); o1.y = f2bf(acc[i][5]); o1.z = f2bf(acc[i][6]); o1.w = f2bf(acc[i][7]);
        *(ushort4*)((unsigned short*)outv + off) = o0;
        *(ushort4*)((unsigned short*)outv + off + 64) = o1;
      }
    }
  }
}

extern "C" void kernel_launch(void* const* d_in, const int* in_sizes, int n_in,
                              void* d_out, int out_size, void* d_ws, size_t ws_size,
                              hipStream_t stream) {
  const void* doc = d_in[0];               // [B][N][T][H]  f32 or bf16 (auto-detected)
  const void* q   = d_in[1];               // [B][U][H]
  const int* dmask = (const int*)d_in[2];  // int32 [B][N][T]
  const int* qmask = (const int*)d_in[3];  // int32 [B][U]

  float* ws = (float*)d_ws;
  float* scores = ws;                                     // 3,072,000
  float* tmax   = ws + 3072000;                           // 10,240
  float* tsum   = ws + 3082240;                           // 10,240
  float* W      = ws + 3092480;                           // 524,288
  int*   flag   = (int*)(ws + 3616768);                   // 4
  unsigned short* QsH = (unsigned short*)(ws + 3616772);  // 262,144 ushorts
  unsigned short* QsL = (unsigned short*)(ws + 3747844);
  unsigned short* Pt  = (unsigned short*)(ws + 3878916);  // 3,072,000 ushorts
  unsigned short* PaH = (unsigned short*)(ws + 5414916);
  unsigned short* PaL = (unsigned short*)(ws + 6950916);
  unsigned short* WtH = (unsigned short*)(ws + 8486916);  // 524,288 ushorts
  unsigned short* WtL = (unsigned short*)(ws + 8749060);
  const size_t need_new = (size_t)9011204 * 4;            // 36.0 MB

  kdetect<<<1, 256, 0, stream>>>((const unsigned short*)doc, flag);
  k0_init<<<2048, 256, 0, stream>>>(q, flag, W, QsH, QsL);
  k1_mfma<<<dim3(47, 8), 512, 0, stream>>>(doc, QsH, QsL, flag, scores);
  k2b_tstats<<<160, 256, 0, stream>>>(scores, dmask, tmax, tsum);
  if (ws_size >= need_new) {
    k2c2<<<12000, 256, 0, stream>>>(scores, qmask, dmask, tmax, tsum, PaH, PaL, Pt);
    k3_mfma<<<dim3(24, 4, 8), 256, 0, stream>>>(Pt, doc, flag, W);
    k35_wt<<<dim3(16, 8), 256, 0, stream>>>(W, WtH, WtL);
    k4_mfma<<<dim3(24, 16, 8), 256, 0, stream>>>(PaH, PaL, WtH, WtL, flag, d_out);
  } else {
    k3_aggdoc<<<dim3(16, 8, 8), 256, 0, stream>>>(scores, doc, dmask, tmax, tsum, flag, W);
    k2_softmax_u<<<12000, 256, 0, stream>>>(scores, qmask);
    k4_out<<<dim3(94, 8, 8), 256, 0, stream>>>(scores, W, flag, d_out);
  }
}

// Round 3
// 398.518 us; speedup vs baseline: 1.1160x; 1.1160x over previous
//
#include <hip/hip_runtime.h>

// Problem sizes (fixed by reference): B=8, N=20, T=300, U=64, H=512, NT=6000
#define BB 8
#define NN 20
#define TT 300
#define UU 64
#define HH 512
#define NT 6000

// ws layout (float slots):
//  scores : [B][NT][U]     off 0          (3,072,000)  raw scores (f32)
//  tmax   : [B][U][N]      off 3,072,000  (10,240)
//  tsum   : [B][U][N]      off 3,082,240  (10,240)
//  W      : [B][U][1024]   off 3,092,480  (524,288)   [0:512]=q f32, [512:1024]=aggdoc f32
//  (unused) off 3,616,768  (4)
//  QsH/QsL: bf16 [B][U][512] x2  off 3,616,772 / 3,747,844
//  Pt     : bf16 [B][NT][U]      off 3,878,916
//  PaH/PaL: bf16 [B][NT][U] x2   off 5,414,916 / 6,950,916
//  WtH/WtL: bf16 [B][1024][64]x2 off 8,486,916 / 8,749,060
//  total = 9,011,204 floats = 36.0 MB

typedef __attribute__((ext_vector_type(4))) float f32x4;
typedef __attribute__((ext_vector_type(8))) short s16x8;

__device__ __forceinline__ float bf2f(unsigned short u) {
  union { unsigned int i; float f; } c; c.i = ((unsigned int)u) << 16; return c.f;
}
__device__ __forceinline__ unsigned short f2bf(float f) {
  union { float f; unsigned int i; } c; c.f = f;
  unsigned int u = c.i;
  unsigned int r = (u + 0x7fffu + ((u >> 16) & 1u)) >> 16;  // RNE
  return (unsigned short)r;
}
// split-bf16: x ~= hi + lo, each exactly representable in bf16. Using
// hi*hi' + hi*lo' + lo*hi' in MFMA keeps relative error ~2^-18 (f32-like).
__device__ __forceinline__ void splitbf(float x, unsigned short& hi, unsigned short& lo) {
  hi = f2bf(x);
  lo = f2bf(x - bf2f(hi));
}
__device__ __forceinline__ f32x4 mfma16(s16x8 a, s16x8 b, f32x4 c) {
  return __builtin_amdgcn_mfma_f32_16x16x32_bf16(a, b, c, 0, 0, 0);
}

// Inline per-block dtype detect (replaces the kdetect kernel + flag dependency).
// Every wave reads the SAME first 256 shorts of doc -> wave-uniform, no barrier.
__device__ __forceinline__ int detect_isf32(const void* docv) {
  const unsigned short* d16 = (const unsigned short*)docv;
  int l = threadIdx.x & 63;
  int cnt = 0;
#pragma unroll
  for (int j = 0; j < 4; ++j) {
    unsigned short v = d16[l * 4 + j];
    int e = (v >> 7) & 0xFF;
    cnt += (e > 140 || (e < 110 && (v & 0x7FFFu) != 0)) ? 1 : 0;
  }
#pragma unroll
  for (int o = 32; o > 0; o >>= 1) cnt += __shfl_xor(cnt, o, 64);
  return cnt >= 32;
}

// ---------------- K0: init W (q as f32, zero aggdoc half) + q split planes ----------
__global__ __launch_bounds__(256) void k0_init(const void* __restrict__ qv,
                                               const void* __restrict__ docv,
                                               float* __restrict__ W,
                                               unsigned short* __restrict__ QsH,
                                               unsigned short* __restrict__ QsL) {
  const int isf32 = detect_isf32(docv);
  int idx = blockIdx.x * 256 + threadIdx.x;  // B*U*1024 = 524288
  int h2 = idx & 1023;
  int bu = idx >> 10;
  float v = 0.0f;
  if (h2 < HH) {
    v = isf32 ? ((const float*)qv)[bu * HH + h2]
              : bf2f(((const unsigned short*)qv)[bu * HH + h2]);
    unsigned short hi, lo;
    splitbf(v, hi, lo);
    QsH[bu * HH + h2] = hi;
    QsL[bu * HH + h2] = lo;
  }
  W[idx] = v;
}

// ---------------- K1 (MFMA, split-bf16): scores = doc . q^T ----------------
// Tile: 64 doc rows x 64 u, 256 threads (4 waves), K=512 in 8 chunks of 64.
// q comes from PRE-SPLIT global planes, staged to LDS by plain 16B copies
// (no split VALU); doc is split once at its f32 read. 752 blocks (94x8).
__global__ __launch_bounds__(256) void k1_mfma(const void* __restrict__ docv,
                                               const unsigned short* __restrict__ QsH,
                                               const unsigned short* __restrict__ QsL,
                                               float* __restrict__ scores) {
  __shared__ __align__(16) unsigned short sDh[64 * 64], sDl[64 * 64];
  __shared__ __align__(16) unsigned short sQh[64 * 64], sQl[64 * 64];
  const int isf32 = detect_isf32(docv);
  const int b = blockIdx.y, kt = blockIdx.x;  // kt 0..93
  const int tid = threadIdx.x;
  const int lane = tid & 63, w = tid >> 6;
  const int l15 = lane & 15, l4 = lane >> 4;
  const int kmax = NT - kt * 64;  // 64, or 48 for last block
  const size_t dbase = (size_t)(b * NT + kt * 64) * HH;
  const size_t qbase = (size_t)b * UU * HH;
  const f32x4 zero = {0.f, 0.f, 0.f, 0.f};
  f32x4 acc[4] = {zero, zero, zero, zero};  // 4 u-tiles for this wave's 16 doc rows

  for (int hc = 0; hc < 8; ++hc) {
    if (hc) __syncthreads();
    // stage doc 64x64 hi/lo (split at read, swizzled LDS)
#pragma unroll
    for (int i = 0; i < 2; ++i) {
      int g = tid + 256 * i;  // 512 groups of 8 elems (64 rows x 8 groups)
      int row = g >> 3, h8 = (g & 7) * 8;
      int addr = (row * 128 + h8 * 2) ^ ((row & 7) << 4);
      float v[8] = {0.f, 0.f, 0.f, 0.f, 0.f, 0.f, 0.f, 0.f};
      if (row < kmax) {
        size_t off = dbase + (size_t)row * HH + hc * 64 + h8;
        if (isf32) {
          const float* df = (const float*)docv;
          float4 a0 = *(const float4*)(df + off);
          float4 a1 = *(const float4*)(df + off + 4);
          v[0] = a0.x; v[1] = a0.y; v[2] = a0.z; v[3] = a0.w;
          v[4] = a1.x; v[5] = a1.y; v[6] = a1.z; v[7] = a1.w;
        } else {
          const unsigned short* db = (const unsigned short*)docv;
          ushort4 a0 = *(const ushort4*)(db + off);
          ushort4 a1 = *(const ushort4*)(db + off + 4);
          v[0] = bf2f(a0.x); v[1] = bf2f(a0.y); v[2] = bf2f(a0.z); v[3] = bf2f(a0.w);
          v[4] = bf2f(a1.x); v[5] = bf2f(a1.y); v[6] = bf2f(a1.z); v[7] = bf2f(a1.w);
        }
      }
      s16x8 vh, vl;
#pragma unroll
      for (int j = 0; j < 8; ++j) {
        unsigned short hh, ll; splitbf(v[j], hh, ll);
        vh[j] = (short)hh; vl[j] = (short)ll;
      }
      *(s16x8*)((char*)sDh + addr) = vh;
      *(s16x8*)((char*)sDl + addr) = vl;
    }
    // stage q 64x64 hi/lo: PLAIN COPIES from pre-split planes (no VALU)
#pragma unroll
    for (int i = 0; i < 2; ++i) {
      int g = tid + 256 * i;
      int row = g >> 3, h8 = (g & 7) * 8;
      int addr = (row * 128 + h8 * 2) ^ ((row & 7) << 4);
      size_t off = qbase + (size_t)row * HH + hc * 64 + h8;
      *(s16x8*)((char*)sQh + addr) = *(const s16x8*)&QsH[off];
      *(s16x8*)((char*)sQl + addr) = *(const s16x8*)&QsL[off];
    }
    __syncthreads();
#pragma unroll
    for (int kb = 0; kb < 2; ++kb) {
      const int off = kb * 64 + l4 * 16;
      const int brow = w * 16 + l15;  // this wave's doc rows
      const int ba = (brow * 128 + off) ^ ((brow & 7) << 4);
      s16x8 bh = *(const s16x8*)((const char*)sDh + ba);
      s16x8 bl = *(const s16x8*)((const char*)sDl + ba);
#pragma unroll
      for (int mt = 0; mt < 4; ++mt) {
        const int arow = mt * 16 + l15;
        const int aa = (arow * 128 + off) ^ ((arow & 7) << 4);
        s16x8 ah = *(const s16x8*)((const char*)sQh + aa);
        s16x8 al = *(const s16x8*)((const char*)sQl + aa);
        acc[mt] = mfma16(ah, bh, acc[mt]);
        acc[mt] = mfma16(ah, bl, acc[mt]);
        acc[mt] = mfma16(al, bh, acc[mt]);
      }
    }
  }
  const int krow = w * 16 + l15;
  if (krow < kmax) {
    size_t ro = ((size_t)b * NT + kt * 64 + krow) * 64;
#pragma unroll
    for (int mt = 0; mt < 4; ++mt)
      *(f32x4*)&scores[ro + mt * 16 + l4 * 4] = acc[mt];
  }
}

// ---------------- K2b: per-(b,u,n) online max/sum over T with doc_mask ----------------
// 512 threads (8 t-groups) to halve the serial online-softmax chain at 160 blocks.
__global__ __launch_bounds__(512) void k2b_tstats(const float* __restrict__ scores,
                                                  const int* __restrict__ dm,
                                                  float* __restrict__ tmax,
                                                  float* __restrict__ tsum) {
  const int b = blockIdx.x / NN;
  const int n = blockIdx.x % NN;
  const int u = threadIdx.x & 63;
  const int tg = threadIdx.x >> 6;  // 0..7
  float m = -__builtin_inff(), s = 0.0f;
  for (int t = tg; t < TT; t += 8) {
    int dmv = dm[(b * NN + n) * TT + t];  // wave-uniform
    if (dmv) {
      float v = scores[((size_t)(b * NT) + n * TT + t) * 64 + u];
      if (v > m) { s = s * __expf(m - v) + 1.0f; m = v; }
      else s += __expf(v - m);
    }
  }
  __shared__ float sm[8][64], ss[8][64];
  sm[tg][u] = m; ss[tg][u] = s;
  __syncthreads();
  if (threadIdx.x < 64) {
    float M = sm[0][u];
#pragma unroll
    for (int i = 1; i < 8; ++i) M = fmaxf(M, sm[i][u]);
    float S = 0.0f;
#pragma unroll
    for (int i = 0; i < 8; ++i) {
      if (ss[i][u] > 0.0f) S += ss[i][u] * __expf(sm[i][u] - M);
    }
    tmax[(b * 64 + u) * NN + n] = M;
    tsum[(b * 64 + u) * NN + n] = S;
  }
}

// ---------------- K2c2: U-softmax -> Pa hi/lo (bf16 split) + t-weights -> Pt (bf16) ----
__global__ __launch_bounds__(256) void k2c2(const float* __restrict__ scores,
                                            const int* __restrict__ qm,
                                            const int* __restrict__ dm,
                                            const float* __restrict__ tmax,
                                            const float* __restrict__ tsum,
                                            unsigned short* __restrict__ PaH,
                                            unsigned short* __restrict__ PaL,
                                            unsigned short* __restrict__ Pt) {
  const int row = blockIdx.x * 4 + (threadIdx.x >> 6);  // 0..47999
  const int u = threadIdx.x & 63;
  const int b = row / NT;
  const int k = row - b * NT;
  const int n = k / TT;
  const float s = scores[(size_t)row * 64 + u];
  const int m = qm[b * 64 + u];
  float v = m ? s : -__builtin_inff();
#pragma unroll
  for (int o = 32; o > 0; o >>= 1) v = fmaxf(v, __shfl_xor(v, o, 64));
  float e = m ? __expf(s - v) : 0.0f;
  float sum = e;
#pragma unroll
  for (int o = 32; o > 0; o >>= 1) sum += __shfl_xor(sum, o, 64);
  float attn = (sum > 0.0f) ? (e / sum) : 0.0f;
  unsigned short hi, lo;
  splitbf(attn, hi, lo);
  PaH[(size_t)row * 64 + u] = hi;
  PaL[(size_t)row * 64 + u] = lo;
  float wgt = 0.0f;
  if (dm[b * NT + k]) {
    float S = tsum[(b * 64 + u) * NN + n];
    if (S > 0.0f) wgt = __expf(s - tmax[(b * 64 + u) * NN + n]) / S;
  }
  Pt[(size_t)row * 64 + u] = f2bf(wgt);
}

// ---------------- K3 (MFMA): aggdoc += Pt^T . doc (split-k atomics into W) ----------
// A = Pt^T (m=u), B = doc (n=h); doc hi/lo split. Staging: each thread loads a
// 4k x 4(u|h) register block, splits + transposes in registers, writes ushort4
// (8 B) columns into swizzled LDS.
__global__ __launch_bounds__(256) void k3_mfma(const unsigned short* __restrict__ Pt,
                                               const void* __restrict__ docv,
                                               float* __restrict__ W) {
  __shared__ __align__(16) unsigned short sDh[128 * 64], sDl[128 * 64];  // [h][k] bf16
  __shared__ __align__(16) unsigned short sP[64 * 64];                   // [u][k] bf16
  const int isf32 = detect_isf32(docv);
  const int b = blockIdx.z, hc = blockIdx.y, kc = blockIdx.x;  // (24,4,8)
  const int tid = threadIdx.x, lane = tid & 63, w = tid >> 6;
  const int l15 = lane & 15, l4 = lane >> 4;
  const int k0base = kc * 250, kend = k0base + 250;
  const f32x4 zero = {0.f, 0.f, 0.f, 0.f};
  f32x4 acc[4][2];
#pragma unroll
  for (int mt = 0; mt < 4; ++mt) { acc[mt][0] = zero; acc[mt][1] = zero; }

  for (int kb = k0base; kb < kend; kb += 64) {
    const int kn = min(64, kend - kb);
    if (kb != k0base) __syncthreads();
    // ---- Pt chunk: 4x4 register transpose -> sP[u][k]
    {
      const int ug = tid & 15, kg = tid >> 4;  // u-group, k-group
      ushort4 r[4];
#pragma unroll
      for (int rr = 0; rr < 4; ++rr) {
        int kk = kg * 4 + rr;
        ushort4 t = make_ushort4(0, 0, 0, 0);
        if (kk < kn) t = *(const ushort4*)&Pt[((size_t)b * NT + kb + kk) * 64 + ug * 4];
        r[rr] = t;
      }
      const unsigned short* rp = (const unsigned short*)r;
#pragma unroll
      for (int uu = 0; uu < 4; ++uu) {
        int u = ug * 4 + uu;
        int addr = (u * 128 + kg * 8) ^ ((u & 7) << 4);
        ushort4 col = make_ushort4(rp[0 * 4 + uu], rp[1 * 4 + uu], rp[2 * 4 + uu], rp[3 * 4 + uu]);
        *(ushort4*)((char*)sP + addr) = col;
      }
    }
    // ---- doc chunk: 4x4 register split+transpose -> sDh/sDl[h][k]
#pragma unroll
    for (int i = 0; i < 2; ++i) {
      int s = tid + 256 * i;          // 512 tasks
      int hg = s & 31, kg = s >> 5;   // h-group (0..31), k-group (0..15)
      float rv[4][4];
#pragma unroll
      for (int rr = 0; rr < 4; ++rr) {
        int kk = kg * 4 + rr;
        float4 v = make_float4(0.f, 0.f, 0.f, 0.f);
        if (kk < kn) {
          size_t off = ((size_t)b * NT + kb + kk) * HH + hc * 128 + hg * 4;
          if (isf32) v = *(const float4*)((const float*)docv + off);
          else {
            ushort4 t = *(const ushort4*)((const unsigned short*)docv + off);
            v = make_float4(bf2f(t.x), bf2f(t.y), bf2f(t.z), bf2f(t.w));
          }
        }
        rv[rr][0] = v.x; rv[rr][1] = v.y; rv[rr][2] = v.z; rv[rr][3] = v.w;
      }
#pragma unroll
      for (int hh = 0; hh < 4; ++hh) {
        int hrow = hg * 4 + hh;
        int addr = (hrow * 128 + kg * 8) ^ ((hrow & 7) << 4);
        unsigned short h0, l0, h1, l1, h2, l2, h3, l3;
        splitbf(rv[0][hh], h0, l0);
        splitbf(rv[1][hh], h1, l1);
        splitbf(rv[2][hh], h2, l2);
        splitbf(rv[3][hh], h3, l3);
        *(ushort4*)((char*)sDh + addr) = make_ushort4(h0, h1, h2, h3);
        *(ushort4*)((char*)sDl + addr) = make_ushort4(l0, l1, l2, l3);
      }
    }
    __syncthreads();
#pragma unroll
    for (int ks = 0; ks < 2; ++ks) {
      const int off = ks * 64 + l4 * 16;
      s16x8 bh[2], bl[2];
#pragma unroll
      for (int nt = 0; nt < 2; ++nt) {
        int r = w * 32 + nt * 16 + l15;
        int a = (r * 128 + off) ^ ((r & 7) << 4);
        bh[nt] = *(const s16x8*)((const char*)sDh + a);
        bl[nt] = *(const s16x8*)((const char*)sDl + a);
      }
#pragma unroll
      for (int mt = 0; mt < 4; ++mt) {
        int r = mt * 16 + l15;
        int a = (r * 128 + off) ^ ((r & 7) << 4);
        s16x8 pa = *(const s16x8*)((const char*)sP + a);
#pragma unroll
        for (int nt = 0; nt < 2; ++nt) {
          acc[mt][nt] = mfma16(pa, bh[nt], acc[mt][nt]);
          acc[mt][nt] = mfma16(pa, bl[nt], acc[mt][nt]);
        }
      }
    }
  }
#pragma unroll
  for (int mt = 0; mt < 4; ++mt)
#pragma unroll
    for (int nt = 0; nt < 2; ++nt)
#pragma unroll
      for (int j = 0; j < 4; ++j) {
        int u = mt * 16 + l4 * 4 + j;
        int h = hc * 128 + w * 32 + nt * 16 + l15;
        atomicAdd(&W[((size_t)b * 64 + u) * 1024 + 512 + h], acc[mt][nt][j]);
      }
}

// ---------------- K3.5: W f32 [b][u][1024] -> Wt hi/lo bf16 [b][1024][64] -----------
__global__ __launch_bounds__(256) void k35_wt(const float* __restrict__ W,
                                              unsigned short* __restrict__ WtH,
                                              unsigned short* __restrict__ WtL) {
  __shared__ float sW[64][68];
  const int b = blockIdx.y, hck = blockIdx.x;  // 16 chunks of 64 h2
  const int tid = threadIdx.x;
#pragma unroll
  for (int i = 0; i < 4; ++i) {
    int g = tid + 256 * i;
    int u = g >> 4, c4 = (g & 15) * 4;
    *(float4*)&sW[u][c4] = *(const float4*)&W[((size_t)b * 64 + u) * 1024 + hck * 64 + c4];
  }
  __syncthreads();
  const int h = tid >> 2, ug = tid & 3;
  s16x8 oh[2], ol[2];
#pragma unroll
  for (int p = 0; p < 2; ++p)
#pragma unroll
    for (int j = 0; j < 8; ++j) {
      unsigned short hh, ll;
      splitbf(sW[ug * 16 + p * 8 + j][h], hh, ll);
      oh[p][j] = (short)hh; ol[p][j] = (short)ll;
    }
  size_t ob = ((size_t)b * 1024 + hck * 64 + h) * 64 + ug * 16;
  *(s16x8*)&WtH[ob] = oh[0];
  *(s16x8*)&WtH[ob + 8] = oh[1];
  *(s16x8*)&WtL[ob] = ol[0];
  *(s16x8*)&WtL[ob + 8] = ol[1];
}

// ---------------- K4 (MFMA): out = Pa . W, fragments straight from L2 ----------------
__global__ __launch_bounds__(256) void k4_mfma(const unsigned short* __restrict__ PaH,
                                               const unsigned short* __restrict__ PaL,
                                               const unsigned short* __restrict__ WtH,
                                               const unsigned short* __restrict__ WtL,
                                               const void* __restrict__ docv,
                                               void* __restrict__ outv) {
  const int isf32 = detect_isf32(docv);
  const int b = blockIdx.z, ht = blockIdx.y, kt = blockIdx.x;  // (24,16,8)
  const int tid = threadIdx.x, lane = tid & 63, w = tid >> 6;
  const int l15 = lane & 15, l4 = lane >> 4;
  const int h0 = ht * 64;
  const int kr0 = kt * 256 + w * 64;
  const f32x4 zero = {0.f, 0.f, 0.f, 0.f};
  f32x4 acc[4][4];
#pragma unroll
  for (int mt = 0; mt < 4; ++mt)
#pragma unroll
    for (int nt = 0; nt < 4; ++nt) acc[mt][nt] = zero;
#pragma unroll
  for (int kb = 0; kb < 2; ++kb) {
    s16x8 ah[4], al[4];
#pragma unroll
    for (int mt = 0; mt < 4; ++mt) {
      size_t a = ((size_t)b * 1024 + h0 + mt * 16 + l15) * 64 + kb * 32 + l4 * 8;
      ah[mt] = *(const s16x8*)&WtH[a];
      al[mt] = *(const s16x8*)&WtL[a];
    }
#pragma unroll
    for (int nt = 0; nt < 4; ++nt) {
      int krow = kr0 + nt * 16 + l15;
      int krc = krow < NT ? krow : NT - 1;  // clamp tail reads (cols never stored)
      size_t pb = ((size_t)b * NT + krc) * 64 + kb * 32 + l4 * 8;
      s16x8 bh = *(const s16x8*)&PaH[pb];
      s16x8 bl = *(const s16x8*)&PaL[pb];
#pragma unroll
      for (int mt = 0; mt < 4; ++mt) {
        acc[mt][nt] = mfma16(ah[mt], bh, acc[mt][nt]);
        acc[mt][nt] = mfma16(ah[mt], bl, acc[mt][nt]);
        acc[mt][nt] = mfma16(al[mt], bh, acc[mt][nt]);
      }
    }
  }
#pragma unroll
  for (int nt = 0; nt < 4; ++nt) {
    int krow = kr0 + nt * 16 + l15;
    if (krow < NT) {
      size_t ob = ((size_t)b * NT + krow) * 1024 + h0;
#pragma unroll
      for (int mt = 0; mt < 4; ++mt) {
        int h2 = mt * 16 + l4 * 4;
        if (isf32) {
          *(f32x4*)((float*)outv + ob + h2) = acc[mt][nt];
        } else {
          ushort4 o;
          o.x = f2bf(acc[mt][nt][0]); o.y = f2bf(acc[mt][nt][1]);
          o.z = f2bf(acc[mt][nt][2]); o.w = f2bf(acc[mt][nt][3]);
          *(ushort4*)((unsigned short*)outv + ob + h2) = o;
        }
      }
    }
  }
}

// ---------------- fallback K2 (in-place U-softmax only, f32) ----------------
__global__ __launch_bounds__(256) void k2_softmax_u(float* __restrict__ scores,
                                                    const int* __restrict__ qm) {
  const int row = blockIdx.x * 4 + (threadIdx.x >> 6);
  const int u = threadIdx.x & 63;
  const int b = row / NT;
  const float s = scores[(size_t)row * 64 + u];
  const int m = qm[b * 64 + u];
  float v = m ? s : -__builtin_inff();
#pragma unroll
  for (int o = 32; o > 0; o >>= 1) v = fmaxf(v, __shfl_xor(v, o, 64));
  float e = m ? __expf(s - v) : 0.0f;
  float sum = e;
#pragma unroll
  for (int o = 32; o > 0; o >>= 1) sum += __shfl_xor(sum, o, 64);
  scores[(size_t)row * 64 + u] = (sum > 0.0f) ? (e / sum) : 0.0f;
}

// ---------------- fallback K3 (original fused aggdoc, f32) ----------------
__global__ __launch_bounds__(256) void k3_aggdoc(const float* __restrict__ scores,
                                                 const void* __restrict__ docv,
                                                 const int* __restrict__ dm,
                                                 const float* __restrict__ tmax,
                                                 const float* __restrict__ tsum,
                                                 float* __restrict__ W) {
  __shared__ float wL[32][68];
  __shared__ float dL[32][68];
  const int isf32 = detect_isf32(docv);
  const int b = blockIdx.z, hc = blockIdx.y, kc = blockIdx.x;  // (16,8,8)
  const int tid = threadIdx.x;
  const int th = tid & 15, tuq = tid >> 4;
  float acc[4][4] = {};
  const int k0base = kc * 375, kend = k0base + 375;
  for (int k0 = k0base; k0 < kend; k0 += 32) {
    const int kn = min(32, kend - k0);
#pragma unroll
    for (int i = 0; i < 8; ++i) {
      int idx = tid + 256 * i;
      int kk = idx >> 6, uu = idx & 63;
      float wv = 0.0f;
      if (kk < kn) {
        int k = k0 + kk;
        int n = k / TT;
        if (dm[b * NT + k]) {
          float S = tsum[(b * 64 + uu) * NN + n];
          if (S > 0.0f) {
            float M = tmax[(b * 64 + uu) * NN + n];
            wv = __expf(scores[((size_t)(b * NT) + k) * 64 + uu] - M) / S;
          }
        }
      }
      wL[kk][uu] = wv;
    }
#pragma unroll
    for (int i = 0; i < 2; ++i) {
      int g = tid + 256 * i;
      int kk = g >> 4, c4 = (g & 15) * 4;
      float4 v = make_float4(0.f, 0.f, 0.f, 0.f);
      if (kk < kn) {
        size_t off = ((size_t)(b * NT) + k0 + kk) * HH + hc * 64 + c4;
        if (isf32) v = *(const float4*)((const float*)docv + off);
        else {
          ushort4 t4 = *(const ushort4*)((const unsigned short*)docv + off);
          v = make_float4(bf2f(t4.x), bf2f(t4.y), bf2f(t4.z), bf2f(t4.w));
        }
      }
      *(float4*)&dL[kk][c4] = v;
    }
    __syncthreads();
    for (int kk = 0; kk < kn; ++kk) {
      float4 w4 = *(const float4*)&wL[kk][tuq * 4];
      float4 d4 = *(const float4*)&dL[kk][th * 4];
      acc[0][0] += w4.x * d4.x; acc[0][1] += w4.x * d4.y; acc[0][2] += w4.x * d4.z; acc[0][3] += w4.x * d4.w;
      acc[1][0] += w4.y * d4.x; acc[1][1] += w4.y * d4.y; acc[1][2] += w4.y * d4.z; acc[1][3] += w4.y * d4.w;
      acc[2][0] += w4.z * d4.x; acc[2][1] += w4.z * d4.y; acc[2][2] += w4.z * d4.z; acc[2][3] += w4.z * d4.w;
      acc[3][0] += w4.w * d4.x; acc[3][1] += w4.w * d4.y; acc[3][2] += w4.w * d4.z; acc[3][3] += w4.w * d4.w;
    }
    __syncthreads();
  }
#pragma unroll
  for (int i = 0; i < 4; ++i) {
#pragma unroll
    for (int j = 0; j < 4; ++j) {
      size_t addr = ((size_t)(b * 64) + tuq * 4 + i) * 1024 + 512 + hc * 64 + th * 4 + j;
      atomicAdd(&W[addr], acc[i][j]);
    }
  }
}

// ---------------- fallback K4 (f32 VALU out-GEMM) ----------------
__global__ __launch_bounds__(256) void k4_out(const float* __restrict__ attn,
                                              const float* __restrict__ W,
                                              const void* __restrict__ docv,
                                              void* __restrict__ outv) {
  __shared__ float sAt[64][68];
  __shared__ float sWt[64][132];
  const int isf32 = detect_isf32(docv);
  const int b = blockIdx.z;
  const int kt = blockIdx.x;
  const int ht = blockIdx.y;
  const int tid = threadIdx.x;
  const int th2 = tid & 15, tkq = tid >> 4;
#pragma unroll
  for (int i = 0; i < 4; ++i) {
    int g = tid + 256 * i;
    int row = g >> 4, c4 = (g & 15) * 4;
    int k = kt * 64 + row;
    float4 v = make_float4(0.f, 0.f, 0.f, 0.f);
    if (k < NT) v = *(const float4*)&attn[((size_t)(b * NT) + k) * 64 + c4];
    *(float4*)&sAt[row][c4] = v;
  }
#pragma unroll
  for (int i = 0; i < 8; ++i) {
    int g = tid + 256 * i;
    int row = g >> 5, c4 = (g & 31) * 4;
    float4 wv = *(const float4*)&W[((size_t)(b * 64) + row) * 1024 + ht * 128 + c4];
    *(float4*)&sWt[row][c4] = wv;
  }
  __syncthreads();
  float acc[4][8] = {};
#pragma unroll 4
  for (int u = 0; u < 64; u += 4) {
    float a[4][4];
#pragma unroll
    for (int i = 0; i < 4; ++i)
      *(float4*)a[i] = *(const float4*)&sAt[tkq * 4 + i][u];
#pragma unroll
    for (int r = 0; r < 4; ++r) {
      float4 w0 = *(const float4*)&sWt[u + r][th2 * 4];
      float4 w1 = *(const float4*)&sWt[u + r][64 + th2 * 4];
#pragma unroll
      for (int i = 0; i < 4; ++i) {
        acc[i][0] += a[i][r] * w0.x; acc[i][1] += a[i][r] * w0.y;
        acc[i][2] += a[i][r] * w0.z; acc[i][3] += a[i][r] * w0.w;
        acc[i][4] += a[i][r] * w1.x; acc[i][5] += a[i][r] * w1.y;
        acc[i][6] += a[i][r] * w1.z; acc[i][7] += a[i][r] * w1.w;
      }
    }
  }
#pragma unroll
  for (int i = 0; i < 4; ++i) {
    int k = kt * 64 + tkq * 4 + i;
    if (k < NT) {
      size_t off = ((size_t)(b * NT) + k) * 1024 + ht * 128 + th2 * 4;
      if (isf32) {
        *(float4*)((float*)outv + off) = make_float4(acc[i][0], acc[i][1], acc[i][2], acc[i][3]);
        *(float4*)((float*)outv + off + 64) = make_float4(acc[i][4], acc[i][5], acc[i][6], acc[i][7]);
      } else {
        ushort4 o0, o1;
        o0.x = f2bf(acc[i][0]); o0.y = f2bf(acc[i][1]); o0.z = f2bf(acc[i][2]); o0.w = f2bf(acc[i][3]);
        o1.x = f2bf(acc[i][4]); o1.y = f2bf(acc[i][5]); o1.z = f2bf(acc[i][6]); o1.w = f2bf(acc[i][7]);
        *(ushort4*)((unsigned short*)outv + off) = o0;
        *(ushort4*)((unsigned short*)outv + off + 64) = o1;
      }
    }
  }
}

extern "C" void kernel_launch(void* const* d_in, const int* in_sizes, int n_in,
                              void* d_out, int out_size, void* d_ws, size_t ws_size,
                              hipStream_t stream) {
  const void* doc = d_in[0];               // [B][N][T][H]  f32 or bf16 (auto-detected)
  const void* q   = d_in[1];               // [B][U][H]
  const int* dmask = (const int*)d_in[2];  // int32 [B][N][T]
  const int* qmask = (const int*)d_in[3];  // int32 [B][U]

  float* ws = (float*)d_ws;
  float* scores = ws;                                     // 3,072,000
  float* tmax   = ws + 3072000;                           // 10,240
  float* tsum   = ws + 3082240;                           // 10,240
  float* W      = ws + 3092480;                           // 524,288
  unsigned short* QsH = (unsigned short*)(ws + 3616772);  // 262,144 ushorts
  unsigned short* QsL = (unsigned short*)(ws + 3747844);
  unsigned short* Pt  = (unsigned short*)(ws + 3878916);  // 3,072,000 ushorts
  unsigned short* PaH = (unsigned short*)(ws + 5414916);
  unsigned short* PaL = (unsigned short*)(ws + 6950916);
  unsigned short* WtH = (unsigned short*)(ws + 8486916);  // 524,288 ushorts
  unsigned short* WtL = (unsigned short*)(ws + 8749060);
  const size_t need_new = (size_t)9011204 * 4;            // 36.0 MB

  k0_init<<<2048, 256, 0, stream>>>(q, doc, W, QsH, QsL);
  k1_mfma<<<dim3(94, 8), 256, 0, stream>>>(doc, QsH, QsL, scores);
  k2b_tstats<<<160, 512, 0, stream>>>(scores, dmask, tmax, tsum);
  if (ws_size >= need_new) {
    k2c2<<<12000, 256, 0, stream>>>(scores, qmask, dmask, tmax, tsum, PaH, PaL, Pt);
    k3_mfma<<<dim3(24, 4, 8), 256, 0, stream>>>(Pt, doc, W);
    k35_wt<<<dim3(16, 8), 256, 0, stream>>>(W, WtH, WtL);
    k4_mfma<<<dim3(24, 16, 8), 256, 0, stream>>>(PaH, PaL, WtH, WtL, doc, d_out);
  } else {
    k3_aggdoc<<<dim3(16, 8, 8), 256, 0, stream>>>(scores, doc, dmask, tmax, tsum, W);
    k2_softmax_u<<<12000, 256, 0, stream>>>(scores, qmask);
    k4_out<<<dim3(94, 8, 8), 256, 0, stream>>>(scores, W, doc, d_out);
  }
}